// Round 20
// baseline (60.485 us; speedup 1.0000x reference)
//
#include <hip/hip_runtime.h>

// ---------------------------------------------------------------------------
// MixModel R20 = R19 with PER-WAVE DMA staging -> barrier 1 deleted.
// Ladder: R10 71.1 | R16 +NT 65.3 | R17 row-pair pk 65.2 | R18 LDS-out 62.0
//   | R19 separate obuf (2 barriers) 59.8.
// R19's remaining serialization: barrier1 makes every wave wait for ALL 9
// DMA loads. But wave w's threads only consume rows rp in [floor(64w/6),
// floor((64w+63)/6)] -> f4 [0..197]/[180..395]/[378..575]. Each wave stages
// its own coverage (4 gload_lds from base B={0,180,320}; overlaps staged
// twice with identical bytes - benign) and waits only on its OWN vmcnt(0).
// sreg written redundantly by each wave (same values). barrier2 (obuf->NT)
// stays. Body/geometry/NT tail identical to R19.
// Tripwires: WRITE >> 141MB or VGPR > 56 -> revert to R19.
// ---------------------------------------------------------------------------

typedef float f2 __attribute__((ext_vector_type(2)));
typedef float fv4 __attribute__((ext_vector_type(4)));

__device__ __forceinline__ f2 splat2(float x) { f2 v; v.x = x; v.y = x; return v; }
__device__ __forceinline__ f2 mk2(float a, float b) { f2 v; v.x = a; v.y = b; return v; }
__device__ __forceinline__ f2 fma2(f2 a, f2 b, f2 c) { return __builtin_elementwise_fma(a, b, c); }
__device__ __forceinline__ f2 relu2(f2 a) { return __builtin_elementwise_max(a, splat2(0.0f)); }

// Packed MLP 3->3->6->3 (pair-axis = 2 rows).
__device__ __forceinline__ void mlp_a2(f2 x0, f2 x1, f2 x2,
                                       const float* __restrict__ w0, const float* __restrict__ b0,
                                       const float* __restrict__ w1, const float* __restrict__ b1,
                                       const float* __restrict__ w2, const float* __restrict__ b2,
                                       f2& o0, f2& o1, f2& o2)
{
    f2 h0[3];
#pragma unroll
    for (int q = 0; q < 3; ++q) {
        f2 a = fma2(x0, splat2(w0[q*3+0]), splat2(b0[q]));
        a = fma2(x1, splat2(w0[q*3+1]), a);
        a = fma2(x2, splat2(w0[q*3+2]), a);
        h0[q] = relu2(a);
    }
    f2 h1[6];
#pragma unroll
    for (int q = 0; q < 6; ++q) {
        f2 a = fma2(h0[0], splat2(w1[q*3+0]), splat2(b1[q]));
        a = fma2(h0[1], splat2(w1[q*3+1]), a);
        a = fma2(h0[2], splat2(w1[q*3+2]), a);
        h1[q] = relu2(a);
    }
    f2 t[3];
#pragma unroll
    for (int q = 0; q < 3; ++q) {
        f2 a = fma2(h1[0], splat2(w2[q*6+0]), splat2(b2[q]));
#pragma unroll
        for (int i = 1; i < 6; ++i) a = fma2(h1[i], splat2(w2[q*6+i]), a);
        t[q] = a;
    }
    o0 = t[0]; o1 = t[1]; o2 = t[2];
}

// Packed MLP 4->4->6->2 (pair-axis = 2 rows).
__device__ __forceinline__ void mlp_b2(f2 x0, f2 x1, f2 x2, f2 x3,
                                       const float* __restrict__ w0, const float* __restrict__ b0,
                                       const float* __restrict__ w1, const float* __restrict__ b1,
                                       const float* __restrict__ w2, const float* __restrict__ b2,
                                       f2& o0, f2& o1)
{
    f2 h0[4];
#pragma unroll
    for (int q = 0; q < 4; ++q) {
        f2 a = fma2(x0, splat2(w0[q*4+0]), splat2(b0[q]));
        a = fma2(x1, splat2(w0[q*4+1]), a);
        a = fma2(x2, splat2(w0[q*4+2]), a);
        a = fma2(x3, splat2(w0[q*4+3]), a);
        h0[q] = relu2(a);
    }
    f2 h1[6];
#pragma unroll
    for (int q = 0; q < 6; ++q) {
        f2 a = fma2(h0[0], splat2(w1[q*4+0]), splat2(b1[q]));
        a = fma2(h0[1], splat2(w1[q*4+1]), a);
        a = fma2(h0[2], splat2(w1[q*4+2]), a);
        a = fma2(h0[3], splat2(w1[q*4+3]), a);
        h1[q] = relu2(a);
    }
    f2 t[2];
#pragma unroll
    for (int q = 0; q < 2; ++q) {
        f2 a = fma2(h1[0], splat2(w2[q*6+0]), splat2(b2[q]));
#pragma unroll
        for (int i = 1; i < 6; ++i) a = fma2(h1[i], splat2(w2[q*6+i]), a);
        t[q] = a;
    }
    o0 = t[0]; o1 = t[1];
}

#define ROWS_PB 64
#define TPB 192   // 3 waves; 64 rows = 32 row-pairs x 6 col-segments = 192

__global__ __launch_bounds__(TPB) void mixmodel_kernel(
    const float* __restrict__ u, const float* __restrict__ reg,
    const float* __restrict__ w10, const float* __restrict__ b10,
    const float* __restrict__ w11, const float* __restrict__ b11,
    const float* __restrict__ w12, const float* __restrict__ b12,
    const float* __restrict__ w20, const float* __restrict__ b20,
    const float* __restrict__ w21, const float* __restrict__ b21,
    const float* __restrict__ w22, const float* __restrict__ b22,
    const float* __restrict__ w30, const float* __restrict__ b30,
    const float* __restrict__ w31, const float* __restrict__ b31,
    const float* __restrict__ w32, const float* __restrict__ b32,
    float* __restrict__ out, int n)
{
    __shared__ float4 s4[ROWS_PB * 9];    // 9216 B input u-tile
    __shared__ float4 o4b[ROWS_PB * 9];   // 9216 B output tile
    __shared__ float  sreg[37];

    const int brow = blockIdx.x * ROWS_PB;
    const int t    = threadIdx.x;
    const int wid  = t >> 6;
    const int lane = t & 63;

    // ---- per-wave DMA staging: wave w covers its own consumers' rows ----
    // wave 0 needs f4 0..197, wave 1: 180..395, wave 2: 378..575.
    // Bases {0,180,320}, 4 x 64-f4 loads each (overlaps duplicated, benign).
    {
        const int bw = (wid == 0) ? 0 : (wid == 1) ? 180 : 320;
        const float4* __restrict__ g = reinterpret_cast<const float4*>(u + (size_t)brow * 36);
#pragma unroll
        for (int k = 0; k < 4; ++k) {
            const int base = bw + k * 64;          // f4 units, wave-uniform
            __builtin_amdgcn_global_load_lds(
                (const __attribute__((address_space(1))) void*)(g + base + lane),
                (__attribute__((address_space(3))) void*)(s4 + base),
                16, 0, 0);
        }
    }
    // sreg written redundantly by EACH wave (no cross-wave sync needed)
    if (lane < 37) sreg[lane] = reg[lane];

    // wave-local drain only — no block barrier before compute
    asm volatile("s_waitcnt vmcnt(0) lgkmcnt(0)" ::: "memory");
    __builtin_amdgcn_sched_barrier(0);

    const int rp = t / 6;              // row-pair 0..31 (rows 2rp, 2rp+1)
    const int s  = t - 6 * rp;         // col-segment 0..5 (cols 6s..6s+5)

    const float* sf = reinterpret_cast<const float*>(s4);
    const int va  = rp * 72 + 6 * s;               // dword idx (row 2rp, col 6s)
    const int vaP = va - 2 + (s == 0 ? 36 : 0);    // pre-edge base (k=-2,-1)
    const int vaT = va + (s == 5 ? -36 : 0);       // tail base (k=6,7)

    // ---- pairs P[k+2] = (u[rA][(6s+k)%36], u[rB][same]), k = -2..7 ----
    f2 P[10];
#pragma unroll
    for (int k = 0; k < 2; ++k) { P[k].x = sf[vaP + k];     P[k].y = sf[vaP + k + 36]; }
#pragma unroll
    for (int k = 0; k < 6; ++k) { P[k + 2].x = sf[va + k];  P[k + 2].y = sf[va + k + 36]; }
#pragma unroll
    for (int k = 6; k < 8; ++k) { P[k + 2].x = sf[vaT + k]; P[k + 2].y = sf[vaT + k + 36]; }

    const f2 r02 = splat2(sreg[0]);
    const float* rb = sreg + 6 * s;    // rb[1..6] = reg[6s+1 .. 6s+6]

    f2 c_[6];                          // cols 6s+0..5, pair = (rowA, rowB)

    // ---- phase 1: MLP1 -> cols 3j+0 ----
#pragma unroll
    for (int J = 0; J < 2; ++J) {
        const int b = 3 * J;           // k-base for j = 2s+J
        f2 a0, a1, a2;
        mlp_a2(P[b], P[b + 2], P[b + 3], w10, b10, w11, b11, w12, b12, a0, a1, a2);
        c_[3*J + 0] = fma2(P[b + 2], splat2(rb[b + 1]), r02)
                    + fma2(a2, P[b + 4], fma2(a1, P[b + 1], a0));
    }
    // ---- phase 2: MLP2 -> cols 3j+1 ----
#pragma unroll
    for (int J = 0; J < 2; ++J) {
        const int b = 3 * J;
        f2 a0, a1, a2;
        mlp_a2(P[b + 2], P[b + 3], P[b + 5], w20, b20, w21, b21, w22, b22, a0, a1, a2);
        c_[3*J + 1] = fma2(P[b + 3], splat2(rb[b + 2]), r02)
                    + fma2(a2, P[b + 4], fma2(a1, P[b + 1], a0));
    }
    // ---- phase 3: MLP3 -> cols 3j+2 ----
#pragma unroll
    for (int J = 0; J < 2; ++J) {
        const int b = 3 * J;
        f2 d0, d1;
        mlp_b2(P[b + 2], P[b + 3], P[b + 5], P[b + 6], w30, b30, w31, b31, w32, b32, d0, d1);
        c_[3*J + 2] = fma2(P[b + 4], splat2(rb[b + 3]), r02)
                    + fma2(d1, P[b + 4], d0);
    }

    // ---- write results to the separate output tile (no WAR, no barrier) ----
    {
        float* sfo = reinterpret_cast<float*>(o4b);   // row-major [64][36]
        f2* wA = reinterpret_cast<f2*>(sfo + va);         // va even -> 8B aligned
        f2* wB = reinterpret_cast<f2*>(sfo + va + 36);
        wA[0] = mk2(c_[0].x, c_[1].x);
        wA[1] = mk2(c_[2].x, c_[3].x);
        wA[2] = mk2(c_[4].x, c_[5].x);
        wB[0] = mk2(c_[0].y, c_[1].y);
        wB[1] = mk2(c_[2].y, c_[3].y);
        wB[2] = mk2(c_[4].y, c_[5].y);
    }
    __syncthreads();                      // single block barrier: obuf ready

    // ---- flat, lane-contiguous NT stores: 3 x 1024B per wave instruction ----
    {
        fv4* __restrict__ ob = reinterpret_cast<fv4*>(out + (size_t)brow * 36);
        const fv4* sv = reinterpret_cast<const fv4*>(o4b);
#pragma unroll
        for (int k = 0; k < 3; ++k) {
            const int idx = t + k * TPB;          // 0..575, lane-contiguous
            __builtin_nontemporal_store(sv[idx], ob + idx);
        }
    }
}

extern "C" void kernel_launch(void* const* d_in, const int* in_sizes, int n_in,
                              void* d_out, int out_size, void* d_ws, size_t ws_size,
                              hipStream_t stream)
{
    const float* u   = (const float*)d_in[1];
    const float* reg = (const float*)d_in[2];
    const float* w10 = (const float*)d_in[3];
    const float* b10 = (const float*)d_in[4];
    const float* w11 = (const float*)d_in[5];
    const float* b11 = (const float*)d_in[6];
    const float* w12 = (const float*)d_in[7];
    const float* b12 = (const float*)d_in[8];
    const float* w20 = (const float*)d_in[9];
    const float* b20 = (const float*)d_in[10];
    const float* w21 = (const float*)d_in[11];
    const float* b21 = (const float*)d_in[12];
    const float* w22 = (const float*)d_in[13];
    const float* b22 = (const float*)d_in[14];
    const float* w30 = (const float*)d_in[15];
    const float* b30 = (const float*)d_in[16];
    const float* w31 = (const float*)d_in[17];
    const float* b31 = (const float*)d_in[18];
    const float* w32 = (const float*)d_in[19];
    const float* b32 = (const float*)d_in[20];
    float* out = (float*)d_out;

    const int n = in_sizes[1] / 36;            // 1,000,000 rows; 64 | n exactly
    const int grid = (n + ROWS_PB - 1) / ROWS_PB;   // 15625 full tiles

    hipLaunchKernelGGL(mixmodel_kernel, dim3(grid), dim3(TPB), 0, stream,
                       u, reg, w10, b10, w11, b11, w12, b12,
                       w20, b20, w21, b21, w22, b22,
                       w30, b30, w31, b31, w32, b32, out, n);
}